// Round 9
// baseline (544.018 us; speedup 1.0000x reference)
//
#include <hip/hip_runtime.h>
#include <hip/hip_bf16.h>

// ============================================================
// 2-layer GCN. Per layer:
//   g = (X @ W) * dinv[row]   -- MFMA bf16 split-precision
//   out_i = relu(dinv_i * (sum_{e:dst=i} g[src_e] + g_i) + b)
// R9: fill/gemm1 PARITY-interleaved in one launch (co-residency);
// scan_base folded into scan_local; h1 bf16; reg-direct MFMA.
// ============================================================

typedef __attribute__((ext_vector_type(8))) short bf16x8;
typedef __attribute__((ext_vector_type(4))) float f32x4;

__device__ inline unsigned short f2bf(float f) {        // RNE
    unsigned u = __float_as_uint(f);
    u = (u + 0x7fff + ((u >> 16) & 1)) >> 16;
    return (unsigned short)u;
}
__device__ inline float bf2f(unsigned short h) {
    return __uint_as_float(((unsigned)h) << 16);
}
__device__ inline float bflo(unsigned u) { return __uint_as_float(u << 16); }
__device__ inline float bfhi(unsigned u) { return __uint_as_float(u & 0xffff0000u); }
__device__ inline unsigned pack_bf16_2(float lo, float hi) {
    return (unsigned)f2bf(lo) | ((unsigned)f2bf(hi) << 16);
}
__device__ inline void cvt8(const float* v, bf16x8& h8, bf16x8& l8) {
    #pragma unroll
    for (int j = 0; j < 8; ++j) {
        unsigned short h = f2bf(v[j]);
        h8[j] = (short)h;
        l8[j] = (short)f2bf(v[j] - bf2f(h));
    }
}

// ---------- prep: wsplit(W1) + wsplit(W2) + degree histogram ----------
__global__ void prep_kernel(const int* __restrict__ dst, int* __restrict__ deg, int E,
        const float* __restrict__ W1, unsigned short* __restrict__ w1h,
        unsigned short* __restrict__ w1l,
        const float* __restrict__ W2, unsigned short* __restrict__ w2h,
        unsigned short* __restrict__ w2l) {
    const int W1B = (256 * 128) / 256;   // 128 blocks
    const int W2B = (128 * 64) / 256;    // 32 blocks
    int b = blockIdx.x;
    if (b < W1B) {                        // W1 split+transpose [K=256][N=128]
        int idx = b * 256 + threadIdx.x;
        int k = idx >> 7, n = idx & 127;
        float v = W1[idx];
        unsigned short h = f2bf(v);
        w1h[(size_t)n * 256 + k] = h;
        w1l[(size_t)n * 256 + k] = f2bf(v - bf2f(h));
    } else if (b < W1B + W2B) {           // W2 split+transpose [K=128][N=64]
        int idx = (b - W1B) * 256 + threadIdx.x;
        int k = idx >> 6, n = idx & 63;
        float v = W2[idx];
        unsigned short h = f2bf(v);
        w2h[(size_t)n * 128 + k] = h;
        w2l[(size_t)n * 128 + k] = f2bf(v - bf2f(h));
    } else {                              // histogram
        int nb = gridDim.x - (W1B + W2B);
        int stride = nb * 256;
        for (int i = (b - W1B - W2B) * 256 + threadIdx.x; i < E; i += stride)
            atomicAdd(&deg[dst[i]], 1);
    }
}

// ---------- scan pass 1: per-4096-block sums; also dinv = 1/sqrt(deg+1) ----------
__global__ __launch_bounds__(1024) void scan_partial_kernel(const int* __restrict__ deg,
        int* __restrict__ psum, float* __restrict__ dinv, int n) {
    __shared__ int wsum[16];
    int tid = threadIdx.x, wave = tid >> 6, lane = tid & 63;
    int i0 = blockIdx.x * 4096 + tid * 4;
    int v0 = 0, v1 = 0, v2 = 0, v3 = 0;
    if (i0 + 3 < n) {
        int4 v = *(const int4*)(deg + i0);
        v0 = v.x; v1 = v.y; v2 = v.z; v3 = v.w;
    } else {
        if (i0 + 0 < n) v0 = deg[i0 + 0];
        if (i0 + 1 < n) v1 = deg[i0 + 1];
        if (i0 + 2 < n) v2 = deg[i0 + 2];
        if (i0 + 3 < n) v3 = deg[i0 + 3];
    }
    if (i0 + 0 < n) dinv[i0 + 0] = 1.0f / sqrtf((float)v0 + 1.0f);
    if (i0 + 1 < n) dinv[i0 + 1] = 1.0f / sqrtf((float)v1 + 1.0f);
    if (i0 + 2 < n) dinv[i0 + 2] = 1.0f / sqrtf((float)v2 + 1.0f);
    if (i0 + 3 < n) dinv[i0 + 3] = 1.0f / sqrtf((float)v3 + 1.0f);
    int s = v0 + v1 + v2 + v3;
    #pragma unroll
    for (int off = 1; off < 64; off <<= 1) s += __shfl_xor(s, off, 64);
    if (lane == 0) wsum[wave] = s;
    __syncthreads();
    if (tid == 0) {
        int t = 0;
        #pragma unroll
        for (int w = 0; w < 16; ++w) t += wsum[w];
        psum[blockIdx.x] = t;
    }
}

// ---------- scan pass 2: local scan + inline base from psum -> offs ----------
__global__ __launch_bounds__(1024) void scan_local_kernel(const int* __restrict__ deg,
        const int* __restrict__ psum, int* __restrict__ offs, int n, int sb) {
    __shared__ int wsum[16];
    int tid = threadIdx.x, wave = tid >> 6, lane = tid & 63;
    int bid = blockIdx.x;
    // inline exclusive base across psum (sb <= 64 small)
    int base = 0, total = 0;
    for (int w = 0; w < sb; ++w) {
        int t = psum[w];
        if (w < bid) base += t;
        total += t;
    }
    if (bid == 0 && tid == 0) offs[n] = total;

    int i0 = bid * 4096 + tid * 4;
    int v0 = 0, v1 = 0, v2 = 0, v3 = 0;
    if (i0 + 3 < n) {
        int4 v = *(const int4*)(deg + i0);
        v0 = v.x; v1 = v.y; v2 = v.z; v3 = v.w;
    } else {
        if (i0 + 0 < n) v0 = deg[i0 + 0];
        if (i0 + 1 < n) v1 = deg[i0 + 1];
        if (i0 + 2 < n) v2 = deg[i0 + 2];
        if (i0 + 3 < n) v3 = deg[i0 + 3];
    }
    int s = v0 + v1 + v2 + v3;
    int x = s;
    #pragma unroll
    for (int off = 1; off < 64; off <<= 1) {
        int y = __shfl_up(x, off, 64);
        if (lane >= off) x += y;
    }
    if (lane == 63) wsum[wave] = x;
    __syncthreads();
    int wbase = 0;
    #pragma unroll
    for (int w = 0; w < 16; ++w)
        if (w < wave) wbase += wsum[w];
    int ex = base + wbase + (x - s);
    if (i0 + 0 < n) offs[i0 + 0] = ex;
    if (i0 + 1 < n) offs[i0 + 1] = ex + v0;
    if (i0 + 2 < n) offs[i0 + 2] = ex + v0 + v1;
    if (i0 + 3 < n) offs[i0 + 3] = ex + v0 + v1 + v2;
}

// ---------- fused: CSR fill ∥ layer-1 GEMM, PARITY-interleaved ----------
// grid = 2*NG blocks. odd bid -> gemm1 (gid = bid>>1), even bid -> fill
// (fid = bid>>1, NG fill blocks grid-stride). Co-residency => overlap.
__global__ __launch_bounds__(256) void fused_fill_gemm1(
        const int* __restrict__ src, const int* __restrict__ dst,
        const int* __restrict__ offs, int* __restrict__ cursor,
        int* __restrict__ csr, int E, int NG,
        const float* __restrict__ X,
        const unsigned short* __restrict__ Wh, const unsigned short* __restrict__ Wl,
        const float* __restrict__ dinv, unsigned short* __restrict__ G, int M) {
    const int bid2 = blockIdx.x >> 1;
    if (!(blockIdx.x & 1)) {                          // ---- fill role ----
        int stride = NG * 256;
        for (int i = bid2 * 256 + threadIdx.x; i < E; i += stride) {
            int d = dst[i];
            int pos = offs[d] + atomicAdd(&cursor[d], 1);
            csr[pos] = src[i];
        }
        return;
    }
    // ---- gemm1 role ----
    constexpr int K = 256;
    const int tid = threadIdx.x;
    const int wv = tid >> 6, ln = tid & 63;
    const int l16 = ln & 15, kseg = ln >> 4;
    const int r0 = bid2 * 128 + wv * 32;

    int rA0 = r0 + l16;       if (rA0 >= M) rA0 = M - 1;
    int rA1 = r0 + 16 + l16;  if (rA1 >= M) rA1 = M - 1;
    const float* pA0 = X + (size_t)rA0 * K + kseg * 8;
    const float* pA1 = X + (size_t)rA1 * K + kseg * 8;

    f32x4 acc[2][8];
    #pragma unroll
    for (int a = 0; a < 2; ++a)
        #pragma unroll
        for (int b = 0; b < 8; ++b) acc[a][b] = 0;

    #pragma unroll 2
    for (int k0 = 0; k0 < K; k0 += 32) {
        bf16x8 ah[2], al[2];
        {
            float4 qa = *(const float4*)(pA0 + k0);
            float4 qb = *(const float4*)(pA0 + k0 + 4);
            float v[8] = {qa.x, qa.y, qa.z, qa.w, qb.x, qb.y, qb.z, qb.w};
            cvt8(v, ah[0], al[0]);
        }
        {
            float4 qa = *(const float4*)(pA1 + k0);
            float4 qb = *(const float4*)(pA1 + k0 + 4);
            float v[8] = {qa.x, qa.y, qa.z, qa.w, qb.x, qb.y, qb.z, qb.w};
            cvt8(v, ah[1], al[1]);
        }
        #pragma unroll
        for (int tc = 0; tc < 8; ++tc) {
            size_t wo = (size_t)(tc * 16 + l16) * K + k0 + kseg * 8;
            bf16x8 bh = *(const bf16x8*)(Wh + wo);
            bf16x8 bl = *(const bf16x8*)(Wl + wo);
            #pragma unroll
            for (int tr = 0; tr < 2; ++tr) {
                acc[tr][tc] = __builtin_amdgcn_mfma_f32_16x16x32_bf16(ah[tr], bh, acc[tr][tc], 0, 0, 0);
                acc[tr][tc] = __builtin_amdgcn_mfma_f32_16x16x32_bf16(al[tr], bh, acc[tr][tc], 0, 0, 0);
                acc[tr][tc] = __builtin_amdgcn_mfma_f32_16x16x32_bf16(ah[tr], bl, acc[tr][tc], 0, 0, 0);
            }
        }
    }

    #pragma unroll
    for (int tr = 0; tr < 2; ++tr) {
        int rbase = r0 + tr * 16 + (ln >> 4) * 4;
        #pragma unroll
        for (int r = 0; r < 4; ++r) {
            int row = rbase + r;
            if (row < M) {
                float dv = dinv[row];
                #pragma unroll
                for (int tc = 0; tc < 8; ++tc)
                    G[(size_t)row * 128 + tc * 16 + l16] = f2bf(acc[tr][tc][r] * dv);
            }
        }
    }
}

// ---------- layer-2 GEMM: A = bf16 h1 direct, W2 split hi/lo ----------
__global__ __launch_bounds__(256) void gemm2_kernel(const unsigned short* __restrict__ H,
        const unsigned short* __restrict__ Wh, const unsigned short* __restrict__ Wl,
        const float* __restrict__ dinv, unsigned short* __restrict__ G, int M) {
    constexpr int K = 128;
    const int tid = threadIdx.x;
    const int wv = tid >> 6, ln = tid & 63;
    const int l16 = ln & 15, kseg = ln >> 4;
    const int r0 = blockIdx.x * 128 + wv * 32;

    int rA0 = r0 + l16;       if (rA0 >= M) rA0 = M - 1;
    int rA1 = r0 + 16 + l16;  if (rA1 >= M) rA1 = M - 1;
    const unsigned short* pA0 = H + (size_t)rA0 * K + kseg * 8;
    const unsigned short* pA1 = H + (size_t)rA1 * K + kseg * 8;

    f32x4 acc[2][4];
    #pragma unroll
    for (int a = 0; a < 2; ++a)
        #pragma unroll
        for (int b = 0; b < 4; ++b) acc[a][b] = 0;

    #pragma unroll
    for (int k0 = 0; k0 < K; k0 += 32) {
        bf16x8 a0 = *(const bf16x8*)(pA0 + k0);
        bf16x8 a1 = *(const bf16x8*)(pA1 + k0);
        #pragma unroll
        for (int tc = 0; tc < 4; ++tc) {
            size_t wo = (size_t)(tc * 16 + l16) * K + k0 + kseg * 8;
            bf16x8 bh = *(const bf16x8*)(Wh + wo);
            bf16x8 bl = *(const bf16x8*)(Wl + wo);
            acc[0][tc] = __builtin_amdgcn_mfma_f32_16x16x32_bf16(a0, bh, acc[0][tc], 0, 0, 0);
            acc[0][tc] = __builtin_amdgcn_mfma_f32_16x16x32_bf16(a0, bl, acc[0][tc], 0, 0, 0);
            acc[1][tc] = __builtin_amdgcn_mfma_f32_16x16x32_bf16(a1, bh, acc[1][tc], 0, 0, 0);
            acc[1][tc] = __builtin_amdgcn_mfma_f32_16x16x32_bf16(a1, bl, acc[1][tc], 0, 0, 0);
        }
    }

    #pragma unroll
    for (int tr = 0; tr < 2; ++tr) {
        int rbase = r0 + tr * 16 + (ln >> 4) * 4;
        #pragma unroll
        for (int r = 0; r < 4; ++r) {
            int row = rbase + r;
            if (row < M) {
                float dv = dinv[row];
                #pragma unroll
                for (int tc = 0; tc < 4; ++tc)
                    G[(size_t)row * 64 + tc * 16 + l16] = f2bf(acc[tr][tc][r] * dv);
            }
        }
    }
}

// ---------- aggregate, F=128, bf16 in / bf16 packed out (h1) ----------
__global__ __launch_bounds__(256) void aggregate128_kernel(const unsigned* __restrict__ G,
        const int* __restrict__ csr, const int* __restrict__ offs,
        const float* __restrict__ dinv, const float* __restrict__ bias,
        unsigned* __restrict__ out, int n) {
    int wave = threadIdx.x >> 6, lane = threadIdx.x & 63;
    int node = blockIdx.x * 4 + wave;
    if (node >= n) return;
    int beg = offs[node], end = offs[node + 1];

    unsigned u = G[(size_t)node * 64 + lane];          // self loop
    float a0 = bflo(u), a1 = bfhi(u);
    int e = beg;
    for (; e + 4 <= end; e += 4) {                     // 4 rows in flight
        int s0 = csr[e], s1 = csr[e + 1], s2 = csr[e + 2], s3 = csr[e + 3];
        unsigned u0 = G[(size_t)s0 * 64 + lane];
        unsigned u1 = G[(size_t)s1 * 64 + lane];
        unsigned u2 = G[(size_t)s2 * 64 + lane];
        unsigned u3 = G[(size_t)s3 * 64 + lane];
        a0 += (bflo(u0) + bflo(u1)) + (bflo(u2) + bflo(u3));
        a1 += (bfhi(u0) + bfhi(u1)) + (bfhi(u2) + bfhi(u3));
    }
    for (; e < end; ++e) {
        unsigned u0 = G[(size_t)csr[e] * 64 + lane];
        a0 += bflo(u0);
        a1 += bfhi(u0);
    }
    float di = dinv[node];
    float rx = fmaxf(fmaf(a0, di, bias[lane * 2 + 0]), 0.0f);
    float ry = fmaxf(fmaf(a1, di, bias[lane * 2 + 1]), 0.0f);
    out[(size_t)node * 64 + lane] = pack_bf16_2(rx, ry);
}

// ---------- aggregate, F=64, bf16 in / fp32 out, split-wave ----------
__global__ __launch_bounds__(256) void aggregate64_kernel(const unsigned* __restrict__ G,
        const int* __restrict__ csr, const int* __restrict__ offs,
        const float* __restrict__ dinv, const float* __restrict__ bias,
        float* __restrict__ out, int n) {
    int wave = threadIdx.x >> 6, lane = threadIdx.x & 63;
    int node = blockIdx.x * 4 + wave;
    if (node >= n) return;
    int beg = offs[node], end = offs[node + 1];
    int half = lane >> 5, col = lane & 31;

    float a0 = 0.0f, a1 = 0.0f;
    if (half == 0) {                                   // self loop on low half
        unsigned u = G[(size_t)node * 32 + col];
        a0 = bflo(u); a1 = bfhi(u);
    }
    int e = beg;
    for (; e + 4 <= end; e += 4) {                     // 4 edges/iter (2 per half)
        int sA = csr[e + half], sB = csr[e + 2 + half];
        unsigned uA = G[(size_t)sA * 32 + col];
        unsigned uB = G[(size_t)sB * 32 + col];
        a0 += bflo(uA) + bflo(uB);
        a1 += bfhi(uA) + bfhi(uB);
    }
    if (e + 2 <= end) {
        int sA = csr[e + half];
        unsigned uA = G[(size_t)sA * 32 + col];
        a0 += bflo(uA);
        a1 += bfhi(uA);
        e += 2;
    }
    if (e < end && half == 0) {
        unsigned uA = G[(size_t)csr[e] * 32 + col];
        a0 += bflo(uA);
        a1 += bfhi(uA);
    }
    a0 += __shfl_down(a0, 32, 64);
    a1 += __shfl_down(a1, 32, 64);
    if (half == 0) {
        float di = dinv[node];
        float2 r;
        r.x = fmaxf(fmaf(a0, di, bias[col * 2 + 0]), 0.0f);
        r.y = fmaxf(fmaf(a1, di, bias[col * 2 + 1]), 0.0f);
        ((float2*)(out + (size_t)node * 64))[col] = r;
    }
}

extern "C" void kernel_launch(void* const* d_in, const int* in_sizes, int n_in,
                              void* d_out, int out_size, void* d_ws, size_t ws_size,
                              hipStream_t stream) {
    const float* x  = (const float*)d_in[0];
    const float* W1 = (const float*)d_in[1];
    const float* b1 = (const float*)d_in[2];
    const float* W2 = (const float*)d_in[3];
    const float* b2 = (const float*)d_in[4];
    const int* edge = (const int*)d_in[5];

    const int IN = 256, H1 = 128, H2 = 64;
    const int E = in_sizes[5] / 2;
    const int N = in_sizes[0] / IN;
    const int* srcp = edge;
    const int* dstp = edge + E;

    char* ws = (char*)d_ws;
    auto alignup = [](size_t v) { return (v + 255) & ~(size_t)255; };
    size_t off = 0;
    size_t degSz = alignup((size_t)N * 4);
    int*            deg    = (int*)(ws + off);            off += degSz;
    int*            cursor = (int*)(ws + off);            off += degSz;
    int*            offs   = (int*)(ws + off);            off += alignup(((size_t)N + 1) * 4);
    float*          dinv   = (float*)(ws + off);          off += degSz;
    int*            psum   = (int*)(ws + off);            off += alignup(64 * 4);
    int*            csr    = (int*)(ws + off);            off += alignup((size_t)E * 4);
    unsigned short* wt1h   = (unsigned short*)(ws + off); off += alignup((size_t)IN * H1 * 2);
    unsigned short* wt1l   = (unsigned short*)(ws + off); off += alignup((size_t)IN * H1 * 2);
    unsigned short* wt2h   = (unsigned short*)(ws + off); off += alignup((size_t)H1 * H2 * 2);
    unsigned short* wt2l   = (unsigned short*)(ws + off); off += alignup((size_t)H1 * H2 * 2);
    unsigned short* g1     = (unsigned short*)(ws + off); off += alignup((size_t)N * H1 * 2);
    unsigned*       h1b    = (unsigned*)(ws + off);       off += alignup((size_t)N * (H1 / 2) * 4);
    unsigned short* g2     = g1;                          // g1 dead after aggregate1

    hipMemsetAsync(deg, 0, 2 * degSz, stream);   // deg + cursor contiguous

    int hgrid = 2048;
    int sb = (N + 4095) / 4096;                  // 25 blocks (<=64 required)

    prep_kernel<<<160 + hgrid, 256, 0, stream>>>(dstp, deg, E, W1, wt1h, wt1l,
                                                 W2, wt2h, wt2l);
    scan_partial_kernel<<<sb, 1024, 0, stream>>>(deg, psum, dinv, N);
    scan_local_kernel<<<sb, 1024, 0, stream>>>(deg, psum, offs, N, sb);

    const int NG = (N + 127) / 128;              // 782 gemm blocks = fill blocks
    fused_fill_gemm1<<<2 * NG, 256, 0, stream>>>(srcp, dstp, offs, cursor, csr, E,
                                                 NG, x, wt1h, wt1l, dinv, g1, N);

    int agrid = (N + 3) / 4;
    aggregate128_kernel<<<agrid, 256, 0, stream>>>((const unsigned*)g1, csr, offs,
                                                   dinv, b1, h1b, N);
    gemm2_kernel<<<NG, 256, 0, stream>>>((const unsigned short*)h1b, wt2h, wt2l,
                                         dinv, g2, N);
    aggregate64_kernel<<<agrid, 256, 0, stream>>>((const unsigned*)g2, csr, offs,
                                                  dinv, b2, (float*)d_out, N);
}

// Round 10
// 534.087 us; speedup vs baseline: 1.0186x; 1.0186x over previous
//
#include <hip/hip_runtime.h>
#include <hip/hip_bf16.h>

// ============================================================
// 2-layer GCN. Per layer:
//   g = (X @ W) * dinv[row]   -- MFMA bf16 split-precision
//   out_i = relu(dinv_i * (sum_{e:dst=i} g[src_e] + g_i) + b)
// R10: de-fused (fusion = register tax, R9); gemm BM=64 reg-direct
// barrier-free (occupancy fix); agg128 ILP=8; h1 bf16.
// ============================================================

typedef __attribute__((ext_vector_type(8))) short bf16x8;
typedef __attribute__((ext_vector_type(4))) float f32x4;

__device__ inline unsigned short f2bf(float f) {        // RNE
    unsigned u = __float_as_uint(f);
    u = (u + 0x7fff + ((u >> 16) & 1)) >> 16;
    return (unsigned short)u;
}
__device__ inline float bf2f(unsigned short h) {
    return __uint_as_float(((unsigned)h) << 16);
}
__device__ inline float bflo(unsigned u) { return __uint_as_float(u << 16); }
__device__ inline float bfhi(unsigned u) { return __uint_as_float(u & 0xffff0000u); }
__device__ inline unsigned pack_bf16_2(float lo, float hi) {
    return (unsigned)f2bf(lo) | ((unsigned)f2bf(hi) << 16);
}
__device__ inline void cvt8(const float* v, bf16x8& h8, bf16x8& l8) {
    #pragma unroll
    for (int j = 0; j < 8; ++j) {
        unsigned short h = f2bf(v[j]);
        h8[j] = (short)h;
        l8[j] = (short)f2bf(v[j] - bf2f(h));
    }
}

// ---------- prep: wsplit(W1) + wsplit(W2) + degree histogram ----------
__global__ void prep_kernel(const int* __restrict__ dst, int* __restrict__ deg, int E,
        const float* __restrict__ W1, unsigned short* __restrict__ w1h,
        unsigned short* __restrict__ w1l,
        const float* __restrict__ W2, unsigned short* __restrict__ w2h,
        unsigned short* __restrict__ w2l) {
    const int W1B = (256 * 128) / 256;   // 128 blocks
    const int W2B = (128 * 64) / 256;    // 32 blocks
    int b = blockIdx.x;
    if (b < W1B) {                        // W1 split+transpose [K=256][N=128]
        int idx = b * 256 + threadIdx.x;
        int k = idx >> 7, n = idx & 127;
        float v = W1[idx];
        unsigned short h = f2bf(v);
        w1h[(size_t)n * 256 + k] = h;
        w1l[(size_t)n * 256 + k] = f2bf(v - bf2f(h));
    } else if (b < W1B + W2B) {           // W2 split+transpose [K=128][N=64]
        int idx = (b - W1B) * 256 + threadIdx.x;
        int k = idx >> 6, n = idx & 63;
        float v = W2[idx];
        unsigned short h = f2bf(v);
        w2h[(size_t)n * 128 + k] = h;
        w2l[(size_t)n * 128 + k] = f2bf(v - bf2f(h));
    } else {                              // histogram
        int nb = gridDim.x - (W1B + W2B);
        int stride = nb * 256;
        for (int i = (b - W1B - W2B) * 256 + threadIdx.x; i < E; i += stride)
            atomicAdd(&deg[dst[i]], 1);
    }
}

// ---------- scan pass 1: per-4096-block sums; also dinv = 1/sqrt(deg+1) ----------
__global__ __launch_bounds__(1024) void scan_partial_kernel(const int* __restrict__ deg,
        int* __restrict__ psum, float* __restrict__ dinv, int n) {
    __shared__ int wsum[16];
    int tid = threadIdx.x, wave = tid >> 6, lane = tid & 63;
    int i0 = blockIdx.x * 4096 + tid * 4;
    int v0 = 0, v1 = 0, v2 = 0, v3 = 0;
    if (i0 + 3 < n) {
        int4 v = *(const int4*)(deg + i0);
        v0 = v.x; v1 = v.y; v2 = v.z; v3 = v.w;
    } else {
        if (i0 + 0 < n) v0 = deg[i0 + 0];
        if (i0 + 1 < n) v1 = deg[i0 + 1];
        if (i0 + 2 < n) v2 = deg[i0 + 2];
        if (i0 + 3 < n) v3 = deg[i0 + 3];
    }
    if (i0 + 0 < n) dinv[i0 + 0] = 1.0f / sqrtf((float)v0 + 1.0f);
    if (i0 + 1 < n) dinv[i0 + 1] = 1.0f / sqrtf((float)v1 + 1.0f);
    if (i0 + 2 < n) dinv[i0 + 2] = 1.0f / sqrtf((float)v2 + 1.0f);
    if (i0 + 3 < n) dinv[i0 + 3] = 1.0f / sqrtf((float)v3 + 1.0f);
    int s = v0 + v1 + v2 + v3;
    #pragma unroll
    for (int off = 1; off < 64; off <<= 1) s += __shfl_xor(s, off, 64);
    if (lane == 0) wsum[wave] = s;
    __syncthreads();
    if (tid == 0) {
        int t = 0;
        #pragma unroll
        for (int w = 0; w < 16; ++w) t += wsum[w];
        psum[blockIdx.x] = t;
    }
}

// ---------- scan pass 2: local scan + inline base from psum -> offs ----------
__global__ __launch_bounds__(1024) void scan_local_kernel(const int* __restrict__ deg,
        const int* __restrict__ psum, int* __restrict__ offs, int n, int sb) {
    __shared__ int wsum[16];
    int tid = threadIdx.x, wave = tid >> 6, lane = tid & 63;
    int bid = blockIdx.x;
    int base = 0, total = 0;
    for (int w = 0; w < sb; ++w) {
        int t = psum[w];
        if (w < bid) base += t;
        total += t;
    }
    if (bid == 0 && tid == 0) offs[n] = total;

    int i0 = bid * 4096 + tid * 4;
    int v0 = 0, v1 = 0, v2 = 0, v3 = 0;
    if (i0 + 3 < n) {
        int4 v = *(const int4*)(deg + i0);
        v0 = v.x; v1 = v.y; v2 = v.z; v3 = v.w;
    } else {
        if (i0 + 0 < n) v0 = deg[i0 + 0];
        if (i0 + 1 < n) v1 = deg[i0 + 1];
        if (i0 + 2 < n) v2 = deg[i0 + 2];
        if (i0 + 3 < n) v3 = deg[i0 + 3];
    }
    int s = v0 + v1 + v2 + v3;
    int x = s;
    #pragma unroll
    for (int off = 1; off < 64; off <<= 1) {
        int y = __shfl_up(x, off, 64);
        if (lane >= off) x += y;
    }
    if (lane == 63) wsum[wave] = x;
    __syncthreads();
    int wbase = 0;
    #pragma unroll
    for (int w = 0; w < 16; ++w)
        if (w < wave) wbase += wsum[w];
    int ex = base + wbase + (x - s);
    if (i0 + 0 < n) offs[i0 + 0] = ex;
    if (i0 + 1 < n) offs[i0 + 1] = ex + v0;
    if (i0 + 2 < n) offs[i0 + 2] = ex + v0 + v1;
    if (i0 + 3 < n) offs[i0 + 3] = ex + v0 + v1 + v2;
}

// ---------- CSR bucket fill (standalone: 8 VGPR, high occupancy) ----------
__global__ void fill_kernel(const int* __restrict__ src, const int* __restrict__ dst,
        const int* __restrict__ offs, int* __restrict__ cursor,
        int* __restrict__ csr, int E) {
    int stride = gridDim.x * blockDim.x;
    for (int i = blockIdx.x * blockDim.x + threadIdx.x; i < E; i += stride) {
        int d = dst[i];
        int pos = offs[d] + atomicAdd(&cursor[d], 1);
        csr[pos] = src[i];
    }
}

// ---------- layer-1 GEMM: BM=64, reg-direct, barrier-free ----------
// 4 waves: wave (wr,wc) owns rows [bid*64+wr*32, +32) x cols [wc*64, +64).
// 3-pass split precision (x_hi*W_hi + x_lo*W_hi + x_hi*W_lo), fp32 accum.
__global__ __launch_bounds__(256) void gemm1_kernel(const float* __restrict__ X,
        const unsigned short* __restrict__ Wh, const unsigned short* __restrict__ Wl,
        const float* __restrict__ dinv, unsigned short* __restrict__ G, int M) {
    constexpr int K = 256;
    const int tid = threadIdx.x;
    const int wv = tid >> 6, ln = tid & 63;
    const int l16 = ln & 15, kseg = ln >> 4;
    const int wr = wv >> 1, wc = wv & 1;
    const int r0 = blockIdx.x * 64 + wr * 32;

    int rA0 = r0 + l16;       if (rA0 >= M) rA0 = M - 1;
    int rA1 = r0 + 16 + l16;  if (rA1 >= M) rA1 = M - 1;
    const float* pA0 = X + (size_t)rA0 * K + kseg * 8;
    const float* pA1 = X + (size_t)rA1 * K + kseg * 8;

    f32x4 acc[2][4];
    #pragma unroll
    for (int a = 0; a < 2; ++a)
        #pragma unroll
        for (int b = 0; b < 4; ++b) acc[a][b] = 0;

    float4 qa0 = *(const float4*)(pA0);        // prefetch k-step 0
    float4 qb0 = *(const float4*)(pA0 + 4);
    float4 qa1 = *(const float4*)(pA1);
    float4 qb1 = *(const float4*)(pA1 + 4);

    #pragma unroll 2
    for (int k0 = 0; k0 < K; k0 += 32) {
        bf16x8 ah[2], al[2];
        {
            float v[8] = {qa0.x, qa0.y, qa0.z, qa0.w, qb0.x, qb0.y, qb0.z, qb0.w};
            cvt8(v, ah[0], al[0]);
        }
        {
            float v[8] = {qa1.x, qa1.y, qa1.z, qa1.w, qb1.x, qb1.y, qb1.z, qb1.w};
            cvt8(v, ah[1], al[1]);
        }
        if (k0 + 32 < K) {                     // prefetch next k-step
            qa0 = *(const float4*)(pA0 + k0 + 32);
            qb0 = *(const float4*)(pA0 + k0 + 36);
            qa1 = *(const float4*)(pA1 + k0 + 32);
            qb1 = *(const float4*)(pA1 + k0 + 36);
        }
        #pragma unroll
        for (int tc = 0; tc < 4; ++tc) {
            size_t wo = (size_t)(wc * 64 + tc * 16 + l16) * K + k0 + kseg * 8;
            bf16x8 bh = *(const bf16x8*)(Wh + wo);
            bf16x8 bl = *(const bf16x8*)(Wl + wo);
            #pragma unroll
            for (int tr = 0; tr < 2; ++tr) {
                acc[tr][tc] = __builtin_amdgcn_mfma_f32_16x16x32_bf16(ah[tr], bh, acc[tr][tc], 0, 0, 0);
                acc[tr][tc] = __builtin_amdgcn_mfma_f32_16x16x32_bf16(al[tr], bh, acc[tr][tc], 0, 0, 0);
                acc[tr][tc] = __builtin_amdgcn_mfma_f32_16x16x32_bf16(ah[tr], bl, acc[tr][tc], 0, 0, 0);
            }
        }
    }

    #pragma unroll
    for (int tr = 0; tr < 2; ++tr) {
        int rbase = r0 + tr * 16 + (ln >> 4) * 4;
        #pragma unroll
        for (int r = 0; r < 4; ++r) {
            int row = rbase + r;
            if (row < M) {
                float dv = dinv[row];
                #pragma unroll
                for (int tc = 0; tc < 4; ++tc)
                    G[(size_t)row * 128 + wc * 64 + tc * 16 + l16] =
                        f2bf(acc[tr][tc][r] * dv);
            }
        }
    }
}

// ---------- layer-2 GEMM: BM=64, A bf16 direct, W2 split hi/lo ----------
// 4 waves x 16 rows each, full 64 cols per wave.
__global__ __launch_bounds__(256) void gemm2_kernel(const unsigned short* __restrict__ H,
        const unsigned short* __restrict__ Wh, const unsigned short* __restrict__ Wl,
        const float* __restrict__ dinv, unsigned short* __restrict__ G, int M) {
    constexpr int K = 128;
    const int tid = threadIdx.x;
    const int wv = tid >> 6, ln = tid & 63;
    const int l16 = ln & 15, kseg = ln >> 4;
    const int r0 = blockIdx.x * 64 + wv * 16;

    int rA0 = r0 + l16;  if (rA0 >= M) rA0 = M - 1;
    const unsigned short* pA0 = H + (size_t)rA0 * K + kseg * 8;

    f32x4 acc[4];
    #pragma unroll
    for (int b = 0; b < 4; ++b) acc[b] = 0;

    #pragma unroll
    for (int k0 = 0; k0 < K; k0 += 32) {
        bf16x8 a0 = *(const bf16x8*)(pA0 + k0);
        #pragma unroll
        for (int tc = 0; tc < 4; ++tc) {
            size_t wo = (size_t)(tc * 16 + l16) * K + k0 + kseg * 8;
            bf16x8 bh = *(const bf16x8*)(Wh + wo);
            bf16x8 bl = *(const bf16x8*)(Wl + wo);
            acc[tc] = __builtin_amdgcn_mfma_f32_16x16x32_bf16(a0, bh, acc[tc], 0, 0, 0);
            acc[tc] = __builtin_amdgcn_mfma_f32_16x16x32_bf16(a0, bl, acc[tc], 0, 0, 0);
        }
    }

    {
        int rbase = r0 + (ln >> 4) * 4;
        #pragma unroll
        for (int r = 0; r < 4; ++r) {
            int row = rbase + r;
            if (row < M) {
                float dv = dinv[row];
                #pragma unroll
                for (int tc = 0; tc < 4; ++tc)
                    G[(size_t)row * 64 + tc * 16 + l16] = f2bf(acc[tc][r] * dv);
            }
        }
    }
}

// ---------- aggregate, F=128, bf16 in / bf16 packed out, ILP=8 ----------
__global__ __launch_bounds__(256) void aggregate128_kernel(const unsigned* __restrict__ G,
        const int* __restrict__ csr, const int* __restrict__ offs,
        const float* __restrict__ dinv, const float* __restrict__ bias,
        unsigned* __restrict__ out, int n) {
    int wave = threadIdx.x >> 6, lane = threadIdx.x & 63;
    int node = blockIdx.x * 4 + wave;
    if (node >= n) return;
    int beg = offs[node], end = offs[node + 1];

    unsigned u = G[(size_t)node * 64 + lane];          // self loop
    float a0 = bflo(u), a1 = bfhi(u);
    int e = beg;
    for (; e + 8 <= end; e += 8) {                     // 8 rows in flight
        unsigned uu[8];
        #pragma unroll
        for (int j = 0; j < 8; ++j) uu[j] = G[(size_t)csr[e + j] * 64 + lane];
        #pragma unroll
        for (int j = 0; j < 8; ++j) { a0 += bflo(uu[j]); a1 += bfhi(uu[j]); }
    }
    for (; e + 4 <= end; e += 4) {
        unsigned uu[4];
        #pragma unroll
        for (int j = 0; j < 4; ++j) uu[j] = G[(size_t)csr[e + j] * 64 + lane];
        #pragma unroll
        for (int j = 0; j < 4; ++j) { a0 += bflo(uu[j]); a1 += bfhi(uu[j]); }
    }
    for (; e < end; ++e) {
        unsigned u0 = G[(size_t)csr[e] * 64 + lane];
        a0 += bflo(u0);
        a1 += bfhi(u0);
    }
    float di = dinv[node];
    float rx = fmaxf(fmaf(a0, di, bias[lane * 2 + 0]), 0.0f);
    float ry = fmaxf(fmaf(a1, di, bias[lane * 2 + 1]), 0.0f);
    out[(size_t)node * 64 + lane] = pack_bf16_2(rx, ry);
}

// ---------- aggregate, F=64, bf16 in / fp32 out, split-wave ----------
__global__ __launch_bounds__(256) void aggregate64_kernel(const unsigned* __restrict__ G,
        const int* __restrict__ csr, const int* __restrict__ offs,
        const float* __restrict__ dinv, const float* __restrict__ bias,
        float* __restrict__ out, int n) {
    int wave = threadIdx.x >> 6, lane = threadIdx.x & 63;
    int node = blockIdx.x * 4 + wave;
    if (node >= n) return;
    int beg = offs[node], end = offs[node + 1];
    int half = lane >> 5, col = lane & 31;

    float a0 = 0.0f, a1 = 0.0f;
    if (half == 0) {                                   // self loop on low half
        unsigned u = G[(size_t)node * 32 + col];
        a0 = bflo(u); a1 = bfhi(u);
    }
    int e = beg;
    for (; e + 8 <= end; e += 8) {                     // 8 edges/iter (4 per half)
        unsigned uu[4];
        #pragma unroll
        for (int j = 0; j < 4; ++j) uu[j] = G[(size_t)csr[e + 2 * j + half] * 32 + col];
        #pragma unroll
        for (int j = 0; j < 4; ++j) { a0 += bflo(uu[j]); a1 += bfhi(uu[j]); }
    }
    for (; e + 2 <= end; e += 2) {
        unsigned uA = G[(size_t)csr[e + half] * 32 + col];
        a0 += bflo(uA);
        a1 += bfhi(uA);
    }
    if (e < end && half == 0) {
        unsigned uA = G[(size_t)csr[e] * 32 + col];
        a0 += bflo(uA);
        a1 += bfhi(uA);
    }
    a0 += __shfl_down(a0, 32, 64);
    a1 += __shfl_down(a1, 32, 64);
    if (half == 0) {
        float di = dinv[node];
        float2 r;
        r.x = fmaxf(fmaf(a0, di, bias[col * 2 + 0]), 0.0f);
        r.y = fmaxf(fmaf(a1, di, bias[col * 2 + 1]), 0.0f);
        ((float2*)(out + (size_t)node * 64))[col] = r;
    }
}

extern "C" void kernel_launch(void* const* d_in, const int* in_sizes, int n_in,
                              void* d_out, int out_size, void* d_ws, size_t ws_size,
                              hipStream_t stream) {
    const float* x  = (const float*)d_in[0];
    const float* W1 = (const float*)d_in[1];
    const float* b1 = (const float*)d_in[2];
    const float* W2 = (const float*)d_in[3];
    const float* b2 = (const float*)d_in[4];
    const int* edge = (const int*)d_in[5];

    const int IN = 256, H1 = 128, H2 = 64;
    const int E = in_sizes[5] / 2;
    const int N = in_sizes[0] / IN;
    const int* srcp = edge;
    const int* dstp = edge + E;

    char* ws = (char*)d_ws;
    auto alignup = [](size_t v) { return (v + 255) & ~(size_t)255; };
    size_t off = 0;
    size_t degSz = alignup((size_t)N * 4);
    int*            deg    = (int*)(ws + off);            off += degSz;
    int*            cursor = (int*)(ws + off);            off += degSz;
    int*            offs   = (int*)(ws + off);            off += alignup(((size_t)N + 1) * 4);
    float*          dinv   = (float*)(ws + off);          off += degSz;
    int*            psum   = (int*)(ws + off);            off += alignup(64 * 4);
    int*            csr    = (int*)(ws + off);            off += alignup((size_t)E * 4);
    unsigned short* wt1h   = (unsigned short*)(ws + off); off += alignup((size_t)IN * H1 * 2);
    unsigned short* wt1l   = (unsigned short*)(ws + off); off += alignup((size_t)IN * H1 * 2);
    unsigned short* wt2h   = (unsigned short*)(ws + off); off += alignup((size_t)H1 * H2 * 2);
    unsigned short* wt2l   = (unsigned short*)(ws + off); off += alignup((size_t)H1 * H2 * 2);
    unsigned short* g1     = (unsigned short*)(ws + off); off += alignup((size_t)N * H1 * 2);
    unsigned*       h1b    = (unsigned*)(ws + off);       off += alignup((size_t)N * (H1 / 2) * 4);
    unsigned short* g2     = g1;                          // g1 dead after aggregate1

    hipMemsetAsync(deg, 0, 2 * degSz, stream);   // deg + cursor contiguous

    int sb = (N + 4095) / 4096;                  // 25 blocks (<=64 required)

    prep_kernel<<<160 + 2048, 256, 0, stream>>>(dstp, deg, E, W1, wt1h, wt1l,
                                                W2, wt2h, wt2l);
    scan_partial_kernel<<<sb, 1024, 0, stream>>>(deg, psum, dinv, N);
    scan_local_kernel<<<sb, 1024, 0, stream>>>(deg, psum, offs, N, sb);
    fill_kernel<<<1024, 256, 0, stream>>>(srcp, dstp, offs, cursor, csr, E);

    int g64 = (N + 63) / 64;                     // 1563 blocks
    int agrid = (N + 3) / 4;

    gemm1_kernel<<<g64, 256, 0, stream>>>(x, wt1h, wt1l, dinv, g1, N);
    aggregate128_kernel<<<agrid, 256, 0, stream>>>((const unsigned*)g1, csr, offs,
                                                   dinv, b1, h1b, N);
    gemm2_kernel<<<g64, 256, 0, stream>>>((const unsigned short*)h1b, wt2h, wt2l,
                                          dinv, g2, N);
    aggregate64_kernel<<<agrid, 256, 0, stream>>>((const unsigned*)g2, csr, offs,
                                                  dinv, b2, (float*)d_out, N);
}

// Round 11
// 495.009 us; speedup vs baseline: 1.0990x; 1.0789x over previous
//
#include <hip/hip_runtime.h>
#include <hip/hip_bf16.h>

// ============================================================
// 2-layer GCN. Per layer:
//   g = (X @ W) * dinv[row]   -- MFMA bf16 split-precision
//   out_i = relu(dinv_i * (sum_{e:dst=i} g[src_e] + g_i) + b)
// R11: persistent W-in-LDS GEMMs (1024 thr, barrier-free k-loop,
// B from LDS), v_cvt_pk_bf16_f32 split. Fill/aggs unchanged.
// ============================================================

typedef __attribute__((ext_vector_type(8))) short bf16x8;
typedef __attribute__((ext_vector_type(4))) float f32x4;

__device__ inline unsigned short f2bf(float f) {        // RNE (epilogue stores)
    unsigned u = __float_as_uint(f);
    u = (u + 0x7fff + ((u >> 16) & 1)) >> 16;
    return (unsigned short)u;
}
__device__ inline float bf2f(unsigned short h) {
    return __uint_as_float(((unsigned)h) << 16);
}
__device__ inline float bflo(unsigned u) { return __uint_as_float(u << 16); }
__device__ inline float bfhi(unsigned u) { return __uint_as_float(u & 0xffff0000u); }
__device__ inline unsigned pack_bf16_2(float lo, float hi) {
    return (unsigned)f2bf(lo) | ((unsigned)f2bf(hi) << 16);
}
__device__ inline unsigned cvtpk(float a, float b) {    // dst = {bf16(b),bf16(a)}
    unsigned r;
    asm("v_cvt_pk_bf16_f32 %0, %1, %2" : "=v"(r) : "v"(a), "v"(b));
    return r;
}
// split 8 fp32 -> hi/lo bf16x8 (residual-exact: rounding mode of hi irrelevant)
__device__ inline void split8(float4 qa, float4 qb, bf16x8& h8, bf16x8& l8) {
    float v0=qa.x, v1=qa.y, v2=qa.z, v3=qa.w, v4=qb.x, v5=qb.y, v6=qb.z, v7=qb.w;
    unsigned h0=cvtpk(v0,v1), h1=cvtpk(v2,v3), h2=cvtpk(v4,v5), h3=cvtpk(v6,v7);
    float r0=v0-bflo(h0), r1=v1-bfhi(h0), r2=v2-bflo(h1), r3=v3-bfhi(h1);
    float r4=v4-bflo(h2), r5=v5-bfhi(h2), r6=v6-bflo(h3), r7=v7-bfhi(h3);
    unsigned l0=cvtpk(r0,r1), l1=cvtpk(r2,r3), l2=cvtpk(r4,r5), l3=cvtpk(r6,r7);
    uint4 H = make_uint4(h0,h1,h2,h3), L = make_uint4(l0,l1,l2,l3);
    h8 = __builtin_bit_cast(bf16x8, H);
    l8 = __builtin_bit_cast(bf16x8, L);
}

// ---------- prep: wsplit(W1) + wsplit(W2) + degree histogram ----------
__global__ void prep_kernel(const int* __restrict__ dst, int* __restrict__ deg, int E,
        const float* __restrict__ W1, unsigned short* __restrict__ w1h,
        unsigned short* __restrict__ w1l,
        const float* __restrict__ W2, unsigned short* __restrict__ w2h,
        unsigned short* __restrict__ w2l) {
    const int W1B = (256 * 128) / 256;   // 128 blocks
    const int W2B = (128 * 64) / 256;    // 32 blocks
    int b = blockIdx.x;
    if (b < W1B) {                        // W1 split+transpose [K=256][N=128]
        int idx = b * 256 + threadIdx.x;
        int k = idx >> 7, n = idx & 127;
        float v = W1[idx];
        unsigned short h = f2bf(v);
        w1h[(size_t)n * 256 + k] = h;
        w1l[(size_t)n * 256 + k] = f2bf(v - bf2f(h));
    } else if (b < W1B + W2B) {           // W2 split+transpose [K=128][N=64]
        int idx = (b - W1B) * 256 + threadIdx.x;
        int k = idx >> 6, n = idx & 63;
        float v = W2[idx];
        unsigned short h = f2bf(v);
        w2h[(size_t)n * 128 + k] = h;
        w2l[(size_t)n * 128 + k] = f2bf(v - bf2f(h));
    } else {                              // histogram
        int nb = gridDim.x - (W1B + W2B);
        int stride = nb * 256;
        for (int i = (b - W1B - W2B) * 256 + threadIdx.x; i < E; i += stride)
            atomicAdd(&deg[dst[i]], 1);
    }
}

// ---------- scan pass 1: per-4096-block sums; also dinv = 1/sqrt(deg+1) ----------
__global__ __launch_bounds__(1024) void scan_partial_kernel(const int* __restrict__ deg,
        int* __restrict__ psum, float* __restrict__ dinv, int n) {
    __shared__ int wsum[16];
    int tid = threadIdx.x, wave = tid >> 6, lane = tid & 63;
    int i0 = blockIdx.x * 4096 + tid * 4;
    int v0 = 0, v1 = 0, v2 = 0, v3 = 0;
    if (i0 + 3 < n) {
        int4 v = *(const int4*)(deg + i0);
        v0 = v.x; v1 = v.y; v2 = v.z; v3 = v.w;
    } else {
        if (i0 + 0 < n) v0 = deg[i0 + 0];
        if (i0 + 1 < n) v1 = deg[i0 + 1];
        if (i0 + 2 < n) v2 = deg[i0 + 2];
        if (i0 + 3 < n) v3 = deg[i0 + 3];
    }
    if (i0 + 0 < n) dinv[i0 + 0] = 1.0f / sqrtf((float)v0 + 1.0f);
    if (i0 + 1 < n) dinv[i0 + 1] = 1.0f / sqrtf((float)v1 + 1.0f);
    if (i0 + 2 < n) dinv[i0 + 2] = 1.0f / sqrtf((float)v2 + 1.0f);
    if (i0 + 3 < n) dinv[i0 + 3] = 1.0f / sqrtf((float)v3 + 1.0f);
    int s = v0 + v1 + v2 + v3;
    #pragma unroll
    for (int off = 1; off < 64; off <<= 1) s += __shfl_xor(s, off, 64);
    if (lane == 0) wsum[wave] = s;
    __syncthreads();
    if (tid == 0) {
        int t = 0;
        #pragma unroll
        for (int w = 0; w < 16; ++w) t += wsum[w];
        psum[blockIdx.x] = t;
    }
}

// ---------- scan pass 2: local scan + inline base from psum -> offs ----------
__global__ __launch_bounds__(1024) void scan_local_kernel(const int* __restrict__ deg,
        const int* __restrict__ psum, int* __restrict__ offs, int n, int sb) {
    __shared__ int wsum[16];
    int tid = threadIdx.x, wave = tid >> 6, lane = tid & 63;
    int bid = blockIdx.x;
    int base = 0, total = 0;
    for (int w = 0; w < sb; ++w) {
        int t = psum[w];
        if (w < bid) base += t;
        total += t;
    }
    if (bid == 0 && tid == 0) offs[n] = total;

    int i0 = bid * 4096 + tid * 4;
    int v0 = 0, v1 = 0, v2 = 0, v3 = 0;
    if (i0 + 3 < n) {
        int4 v = *(const int4*)(deg + i0);
        v0 = v.x; v1 = v.y; v2 = v.z; v3 = v.w;
    } else {
        if (i0 + 0 < n) v0 = deg[i0 + 0];
        if (i0 + 1 < n) v1 = deg[i0 + 1];
        if (i0 + 2 < n) v2 = deg[i0 + 2];
        if (i0 + 3 < n) v3 = deg[i0 + 3];
    }
    int s = v0 + v1 + v2 + v3;
    int x = s;
    #pragma unroll
    for (int off = 1; off < 64; off <<= 1) {
        int y = __shfl_up(x, off, 64);
        if (lane >= off) x += y;
    }
    if (lane == 63) wsum[wave] = x;
    __syncthreads();
    int wbase = 0;
    #pragma unroll
    for (int w = 0; w < 16; ++w)
        if (w < wave) wbase += wsum[w];
    int ex = base + wbase + (x - s);
    if (i0 + 0 < n) offs[i0 + 0] = ex;
    if (i0 + 1 < n) offs[i0 + 1] = ex + v0;
    if (i0 + 2 < n) offs[i0 + 2] = ex + v0 + v1;
    if (i0 + 3 < n) offs[i0 + 3] = ex + v0 + v1 + v2;
}

// ---------- CSR bucket fill ----------
__global__ void fill_kernel(const int* __restrict__ src, const int* __restrict__ dst,
        const int* __restrict__ offs, int* __restrict__ cursor,
        int* __restrict__ csr, int E) {
    int stride = gridDim.x * blockDim.x;
    for (int i = blockIdx.x * blockDim.x + threadIdx.x; i < E; i += stride) {
        int d = dst[i];
        int pos = offs[d] + atomicAdd(&cursor[d], 1);
        csr[pos] = src[i];
    }
}

// ---------- layer-1 GEMM: W1 (hi+lo) persistent in LDS, barrier-free ----------
// 1024 thr = 16 waves (4 rowg x 4 colq); wave = 64 rows x 32 cols.
// LDS layout [k/8][n] of uint4 (8 bf16): 2-way bank aliasing only.
__global__ __launch_bounds__(1024, 4) void gemm1_kernel(const float* __restrict__ X,
        const unsigned short* __restrict__ Wh, const unsigned short* __restrict__ Wl,
        const float* __restrict__ dinv, unsigned short* __restrict__ G, int M) {
    __shared__ uint4 LH[4096];           // 64KB  (32 kblk x 128 n)
    __shared__ uint4 LL[4096];           // 64KB
    const int tid = threadIdx.x;
    {
        const uint4* gh = (const uint4*)Wh;
        const uint4* gl = (const uint4*)Wl;
        #pragma unroll
        for (int j = 0; j < 4; ++j) {
            int i = tid + j * 1024;
            int kb = i >> 7, n = i & 127;
            LH[i] = gh[n * 32 + kb];
            LL[i] = gl[n * 32 + kb];
        }
    }
    __syncthreads();                     // only barrier; W read-only after

    const int wv = tid >> 6, ln = tid & 63;
    const int l16 = ln & 15, kseg = ln >> 4;
    const int wr = wv >> 2, wc = wv & 3;
    const int r0 = blockIdx.x * 256 + wr * 64;

    const float* pA[4];
    #pragma unroll
    for (int tr = 0; tr < 4; ++tr) {
        int rr = r0 + tr * 16 + l16;
        if (rr >= M) rr = M - 1;
        pA[tr] = X + (size_t)rr * 256 + kseg * 8;
    }

    f32x4 acc[4][2];
    #pragma unroll
    for (int a = 0; a < 4; ++a)
        #pragma unroll
        for (int b = 0; b < 2; ++b) acc[a][b] = 0;

    for (int k0 = 0; k0 < 256; k0 += 32) {           // 8 iters
        const int kb4 = (k0 >> 3) + kseg;
        bf16x8 bh[2], bl[2];
        #pragma unroll
        for (int tc = 0; tc < 2; ++tc) {
            int li = kb4 * 128 + wc * 32 + tc * 16 + l16;
            bh[tc] = __builtin_bit_cast(bf16x8, LH[li]);
            bl[tc] = __builtin_bit_cast(bf16x8, LL[li]);
        }
        #pragma unroll
        for (int tr = 0; tr < 4; ++tr) {
            float4 qa = *(const float4*)(pA[tr] + k0);
            float4 qb = *(const float4*)(pA[tr] + k0 + 4);
            bf16x8 ah, al;
            split8(qa, qb, ah, al);
            #pragma unroll
            for (int tc = 0; tc < 2; ++tc) {
                acc[tr][tc] = __builtin_amdgcn_mfma_f32_16x16x32_bf16(ah, bh[tc], acc[tr][tc], 0, 0, 0);
                acc[tr][tc] = __builtin_amdgcn_mfma_f32_16x16x32_bf16(al, bh[tc], acc[tr][tc], 0, 0, 0);
                acc[tr][tc] = __builtin_amdgcn_mfma_f32_16x16x32_bf16(ah, bl[tc], acc[tr][tc], 0, 0, 0);
            }
        }
    }

    #pragma unroll
    for (int tr = 0; tr < 4; ++tr) {
        int rbase = r0 + tr * 16 + (ln >> 4) * 4;
        #pragma unroll
        for (int r = 0; r < 4; ++r) {
            int row = rbase + r;
            if (row < M) {
                float dv = dinv[row];
                #pragma unroll
                for (int tc = 0; tc < 2; ++tc)
                    G[(size_t)row * 128 + wc * 32 + tc * 16 + l16] =
                        f2bf(acc[tr][tc][r] * dv);
            }
        }
    }
}

// ---------- layer-2 GEMM: W2 (hi+lo) in LDS, A = bf16 h1 direct ----------
// 1024 thr = 16 waves (8 rowg x 2 colh); wave = 64 rows x 32 cols.
__global__ __launch_bounds__(1024, 4) void gemm2_kernel(const unsigned short* __restrict__ H,
        const unsigned short* __restrict__ Wh, const unsigned short* __restrict__ Wl,
        const float* __restrict__ dinv, unsigned short* __restrict__ G, int M) {
    __shared__ uint4 LH[1024];           // 16KB (16 kblk x 64 n)
    __shared__ uint4 LL[1024];           // 16KB
    const int tid = threadIdx.x;
    {
        int kb = tid >> 6, n = tid & 63;
        LH[tid] = ((const uint4*)Wh)[n * 16 + kb];
        LL[tid] = ((const uint4*)Wl)[n * 16 + kb];
    }
    __syncthreads();

    const int wv = tid >> 6, ln = tid & 63;
    const int l16 = ln & 15, kseg = ln >> 4;
    const int wr = wv >> 1, wc = wv & 1;
    const int r0 = blockIdx.x * 512 + wr * 64;

    const unsigned short* pA[4];
    #pragma unroll
    for (int tr = 0; tr < 4; ++tr) {
        int rr = r0 + tr * 16 + l16;
        if (rr >= M) rr = M - 1;
        pA[tr] = H + (size_t)rr * 128 + kseg * 8;
    }

    f32x4 acc[4][2];
    #pragma unroll
    for (int a = 0; a < 4; ++a)
        #pragma unroll
        for (int b = 0; b < 2; ++b) acc[a][b] = 0;

    for (int k0 = 0; k0 < 128; k0 += 32) {           // 4 iters
        const int kb4 = (k0 >> 3) + kseg;
        bf16x8 bh[2], bl[2];
        #pragma unroll
        for (int tc = 0; tc < 2; ++tc) {
            int li = kb4 * 64 + wc * 32 + tc * 16 + l16;
            bh[tc] = __builtin_bit_cast(bf16x8, LH[li]);
            bl[tc] = __builtin_bit_cast(bf16x8, LL[li]);
        }
        #pragma unroll
        for (int tr = 0; tr < 4; ++tr) {
            bf16x8 a0 = *(const bf16x8*)(pA[tr] + k0);
            #pragma unroll
            for (int tc = 0; tc < 2; ++tc) {
                acc[tr][tc] = __builtin_amdgcn_mfma_f32_16x16x32_bf16(a0, bh[tc], acc[tr][tc], 0, 0, 0);
                acc[tr][tc] = __builtin_amdgcn_mfma_f32_16x16x32_bf16(a0, bl[tc], acc[tr][tc], 0, 0, 0);
            }
        }
    }

    #pragma unroll
    for (int tr = 0; tr < 4; ++tr) {
        int rbase = r0 + tr * 16 + (ln >> 4) * 4;
        #pragma unroll
        for (int r = 0; r < 4; ++r) {
            int row = rbase + r;
            if (row < M) {
                float dv = dinv[row];
                #pragma unroll
                for (int tc = 0; tc < 2; ++tc)
                    G[(size_t)row * 64 + wc * 32 + tc * 16 + l16] =
                        f2bf(acc[tr][tc][r] * dv);
            }
        }
    }
}

// ---------- aggregate, F=128, bf16 in / bf16 packed out, ILP=8 ----------
__global__ __launch_bounds__(256) void aggregate128_kernel(const unsigned* __restrict__ G,
        const int* __restrict__ csr, const int* __restrict__ offs,
        const float* __restrict__ dinv, const float* __restrict__ bias,
        unsigned* __restrict__ out, int n) {
    int wave = threadIdx.x >> 6, lane = threadIdx.x & 63;
    int node = blockIdx.x * 4 + wave;
    if (node >= n) return;
    int beg = offs[node], end = offs[node + 1];

    unsigned u = G[(size_t)node * 64 + lane];          // self loop
    float a0 = bflo(u), a1 = bfhi(u);
    int e = beg;
    for (; e + 8 <= end; e += 8) {                     // 8 rows in flight
        unsigned uu[8];
        #pragma unroll
        for (int j = 0; j < 8; ++j) uu[j] = G[(size_t)csr[e + j] * 64 + lane];
        #pragma unroll
        for (int j = 0; j < 8; ++j) { a0 += bflo(uu[j]); a1 += bfhi(uu[j]); }
    }
    for (; e + 4 <= end; e += 4) {
        unsigned uu[4];
        #pragma unroll
        for (int j = 0; j < 4; ++j) uu[j] = G[(size_t)csr[e + j] * 64 + lane];
        #pragma unroll
        for (int j = 0; j < 4; ++j) { a0 += bflo(uu[j]); a1 += bfhi(uu[j]); }
    }
    for (; e < end; ++e) {
        unsigned u0 = G[(size_t)csr[e] * 64 + lane];
        a0 += bflo(u0);
        a1 += bfhi(u0);
    }
    float di = dinv[node];
    float rx = fmaxf(fmaf(a0, di, bias[lane * 2 + 0]), 0.0f);
    float ry = fmaxf(fmaf(a1, di, bias[lane * 2 + 1]), 0.0f);
    out[(size_t)node * 64 + lane] = pack_bf16_2(rx, ry);
}

// ---------- aggregate, F=64, bf16 in / fp32 out, split-wave ----------
__global__ __launch_bounds__(256) void aggregate64_kernel(const unsigned* __restrict__ G,
        const int* __restrict__ csr, const int* __restrict__ offs,
        const float* __restrict__ dinv, const float* __restrict__ bias,
        float* __restrict__ out, int n) {
    int wave = threadIdx.x >> 6, lane = threadIdx.x & 63;
    int node = blockIdx.x * 4 + wave;
    if (node >= n) return;
    int beg = offs[node], end = offs[node + 1];
    int half = lane >> 5, col = lane & 31;

    float a0 = 0.0f, a1 = 0.0f;
    if (half == 0) {                                   // self loop on low half
        unsigned u = G[(size_t)node * 32 + col];
        a0 = bflo(u); a1 = bfhi(u);
    }
    int e = beg;
    for (; e + 8 <= end; e += 8) {                     // 8 edges/iter (4 per half)
        unsigned uu[4];
        #pragma unroll
        for (int j = 0; j < 4; ++j) uu[j] = G[(size_t)csr[e + 2 * j + half] * 32 + col];
        #pragma unroll
        for (int j = 0; j < 4; ++j) { a0 += bflo(uu[j]); a1 += bfhi(uu[j]); }
    }
    for (; e + 2 <= end; e += 2) {
        unsigned uA = G[(size_t)csr[e + half] * 32 + col];
        a0 += bflo(uA);
        a1 += bfhi(uA);
    }
    if (e < end && half == 0) {
        unsigned uA = G[(size_t)csr[e] * 32 + col];
        a0 += bflo(uA);
        a1 += bfhi(uA);
    }
    a0 += __shfl_down(a0, 32, 64);
    a1 += __shfl_down(a1, 32, 64);
    if (half == 0) {
        float di = dinv[node];
        float2 r;
        r.x = fmaxf(fmaf(a0, di, bias[col * 2 + 0]), 0.0f);
        r.y = fmaxf(fmaf(a1, di, bias[col * 2 + 1]), 0.0f);
        ((float2*)(out + (size_t)node * 64))[col] = r;
    }
}

extern "C" void kernel_launch(void* const* d_in, const int* in_sizes, int n_in,
                              void* d_out, int out_size, void* d_ws, size_t ws_size,
                              hipStream_t stream) {
    const float* x  = (const float*)d_in[0];
    const float* W1 = (const float*)d_in[1];
    const float* b1 = (const float*)d_in[2];
    const float* W2 = (const float*)d_in[3];
    const float* b2 = (const float*)d_in[4];
    const int* edge = (const int*)d_in[5];

    const int IN = 256, H1 = 128, H2 = 64;
    const int E = in_sizes[5] / 2;
    const int N = in_sizes[0] / IN;
    const int* srcp = edge;
    const int* dstp = edge + E;

    char* ws = (char*)d_ws;
    auto alignup = [](size_t v) { return (v + 255) & ~(size_t)255; };
    size_t off = 0;
    size_t degSz = alignup((size_t)N * 4);
    int*            deg    = (int*)(ws + off);            off += degSz;
    int*            cursor = (int*)(ws + off);            off += degSz;
    int*            offs   = (int*)(ws + off);            off += alignup(((size_t)N + 1) * 4);
    float*          dinv   = (float*)(ws + off);          off += degSz;
    int*            psum   = (int*)(ws + off);            off += alignup(64 * 4);
    int*            csr    = (int*)(ws + off);            off += alignup((size_t)E * 4);
    unsigned short* wt1h   = (unsigned short*)(ws + off); off += alignup((size_t)IN * H1 * 2);
    unsigned short* wt1l   = (unsigned short*)(ws + off); off += alignup((size_t)IN * H1 * 2);
    unsigned short* wt2h   = (unsigned short*)(ws + off); off += alignup((size_t)H1 * H2 * 2);
    unsigned short* wt2l   = (unsigned short*)(ws + off); off += alignup((size_t)H1 * H2 * 2);
    unsigned short* g1     = (unsigned short*)(ws + off); off += alignup((size_t)N * H1 * 2);
    unsigned*       h1b    = (unsigned*)(ws + off);       off += alignup((size_t)N * (H1 / 2) * 4);
    unsigned short* g2     = g1;                          // g1 dead after aggregate1

    hipMemsetAsync(deg, 0, 2 * degSz, stream);   // deg + cursor contiguous

    int sb = (N + 4095) / 4096;                  // 25 blocks (<=64 required)

    prep_kernel<<<160 + 2048, 256, 0, stream>>>(dstp, deg, E, W1, wt1h, wt1l,
                                                W2, wt2h, wt2l);
    scan_partial_kernel<<<sb, 1024, 0, stream>>>(deg, psum, dinv, N);
    scan_local_kernel<<<sb, 1024, 0, stream>>>(deg, psum, offs, N, sb);
    fill_kernel<<<1024, 256, 0, stream>>>(srcp, dstp, offs, cursor, csr, E);

    int g1grid = (N + 255) / 256;                // 391 blocks, 256 rows each
    int g2grid = (N + 511) / 512;                // 196 blocks, 512 rows each
    int agrid  = (N + 3) / 4;

    gemm1_kernel<<<g1grid, 1024, 0, stream>>>(x, wt1h, wt1l, dinv, g1, N);
    aggregate128_kernel<<<agrid, 256, 0, stream>>>((const unsigned*)g1, csr, offs,
                                                   dinv, b1, h1b, N);
    gemm2_kernel<<<g2grid, 1024, 0, stream>>>((const unsigned short*)h1b, wt2h, wt2l,
                                              dinv, g2, N);
    aggregate64_kernel<<<agrid, 256, 0, stream>>>((const unsigned*)g2, csr, offs,
                                                  dinv, b2, (float*)d_out, N);
}